// Round 5
// baseline (564.396 us; speedup 1.0000x reference)
//
#include <hip/hip_runtime.h>
#include <hip/hip_bf16.h>
#include <stdint.h>

#define NN 4096
#define H4 4

typedef __hip_bfloat16 bf16;
typedef unsigned short ushort_t;
typedef unsigned long long ull_t;
typedef __attribute__((ext_vector_type(4))) float f32x4;
typedef __attribute__((ext_vector_type(8))) short s16x8;

__device__ __forceinline__ float cvt(float v) { return v; }
__device__ __forceinline__ float cvt(bf16 v) { return __bfloat162float(v); }
__device__ __forceinline__ float lrelu(float z) { return z > 0.f ? z : 0.2f * z; }
__device__ __forceinline__ void sto(float* p, float v) { *p = v; }
__device__ __forceinline__ void sto(bf16* p, float v) { *p = __float2bfloat16(v); }
// f32 -> bf16 RNE bit-trick (scalar path, used by transpose)
__device__ __forceinline__ ushort_t f2bf(float f) {
  unsigned u = __float_as_uint(f);
  return (ushort_t)((u + 0x7fff + ((u >> 16) & 1)) >> 16);
}
// packed pair f32x2 -> bf16x2 (v_cvt_pk_bf16_f32)
__device__ __forceinline__ short2 pkbf(float a, float b) {
  union { __hip_bfloat162 h; short2 s; } u;
  u.h = __float22bfloat162_rn(make_float2(a, b));
  return u.s;
}
__device__ __forceinline__ s16x8 as_s16x8(uint4 v) {
  union { uint4 u; s16x8 s; } c; c.u = v; return c.s;
}

// ---------------- adj -> 64-bit row masks ----------------
__global__ __launch_bounds__(256) void k_mask(const int* __restrict__ adj,
                                              ull_t* __restrict__ mask) {
  int row = blockIdx.x, tid = threadIdx.x;
  int lane = tid & 63, wv = tid >> 6;
  const int* arow = adj + (size_t)row * NN;
  for (int c = 0; c < NN; c += 256) {
    int col = c + wv * 64 + lane;
    ull_t b = __ballot(arow[col] != 0);
    if (lane == 0) mask[row * 64 + (c >> 6) + wv] = b;
  }
}

// ---------------- tiled GEMM: C[M,N] = A[M,K] @ B[K,N] (+bias) ----------------
template <typename TA>
__global__ __launch_bounds__(256) void k_gemm(const TA* __restrict__ A,
                                              const float* __restrict__ B,
                                              const float* __restrict__ bias,
                                              float* __restrict__ C, int M, int K, int Nc) {
  __shared__ float As[16][68];
  __shared__ float Bs[16][68];
  int tid = threadIdx.x;
  int tx = tid & 15, ty = tid >> 4;
  int mBase = blockIdx.y * 64, nBase = blockIdx.x * 64;
  float acc[4][4] = {};
  for (int k0 = 0; k0 < K; k0 += 16) {
#pragma unroll
    for (int l = 0; l < 4; ++l) {
      int idx = l * 256 + tid;
      int m = idx >> 4, k = idx & 15;
      As[k][m] = cvt(A[(size_t)(mBase + m) * K + (k0 + k)]);
    }
#pragma unroll
    for (int l = 0; l < 4; ++l) {
      int idx = l * 256 + tid;
      int k = idx >> 6, n = idx & 63;
      int gn = nBase + n;
      Bs[k][n] = (gn < Nc) ? B[(size_t)(k0 + k) * Nc + gn] : 0.f;
    }
    __syncthreads();
#pragma unroll
    for (int k = 0; k < 16; ++k) {
      float4 a = *(const float4*)&As[k][ty * 4];
      float4 b = *(const float4*)&Bs[k][tx * 4];
      float av[4] = {a.x, a.y, a.z, a.w};
      float bv[4] = {b.x, b.y, b.z, b.w};
#pragma unroll
      for (int r = 0; r < 4; ++r)
#pragma unroll
        for (int c = 0; c < 4; ++c) acc[r][c] += av[r] * bv[c];
    }
    __syncthreads();
  }
#pragma unroll
  for (int r = 0; r < 4; ++r) {
    int gm = mBase + ty * 4 + r;
#pragma unroll
    for (int c = 0; c < 4; ++c) {
      int gn = nBase + tx * 4 + c;
      if (gn < Nc) {
        float v = acc[r][c];
        if (bias) v += bias[gn];
        C[(size_t)gm * Nc + gn] = v;
      }
    }
  }
}

// ---------------- h[N][FT] f32 -> hT[FT][N] bf16 ----------------
template <int FT>
__global__ __launch_bounds__(256) void k_transpose(const float* __restrict__ h,
                                                   ushort_t* __restrict__ hT) {
  int t = threadIdx.x;
  int j = (blockIdx.x << 6) + (t & 63);
  int f0 = blockIdx.y * 16 + (t >> 6) * 4;
  float4 v = *(const float4*)&h[(size_t)j * FT + f0];
  hT[(size_t)(f0 + 0) * NN + j] = f2bf(v.x);
  hT[(size_t)(f0 + 1) * NN + j] = f2bf(v.y);
  hT[(size_t)(f0 + 2) * NN + j] = f2bf(v.z);
  hT[(size_t)(f0 + 3) * NN + j] = f2bf(v.w);
}

// ---------------- attention scores ----------------
template <int F>
__global__ __launch_bounds__(256) void k_scores(const float* __restrict__ h,
                                                const float* __restrict__ a_s,
                                                const float* __restrict__ a_d,
                                                float* __restrict__ es, float* __restrict__ ed) {
  int idx = blockIdx.x * 256 + threadIdx.x;
  if (idx >= NN * H4) return;
  int n = idx >> 2, hd = idx & 3;
  const float* hp = h + (size_t)n * (H4 * F) + hd * F;
  const float* sp = a_s + hd * F;
  const float* dp = a_d + hd * F;
  float ss = 0.f, sd = 0.f;
#pragma unroll 4
  for (int f = 0; f < F; ++f) {
    float v = hp[f];
    ss += v * sp[f];
    sd += v * dp[f];
  }
  es[hd * NN + n] = ss;
  ed[hd * NN + n] = sd;
}

// ---------------- masked-softmax stats (exact fp invariant: z <= me) --------
__global__ __launch_bounds__(256) void k_stats(const float* __restrict__ es,
                                               const float* __restrict__ ed,
                                               const ull_t* __restrict__ mask,
                                               float* __restrict__ mout, float* __restrict__ linv) {
  int i = blockIdx.x, tid = threadIdx.x;
  int hd = tid >> 6, lane = tid & 63;
  const ull_t* mrow = mask + (size_t)i * 64;
  const float* edh = ed + hd * NN;
  float esi = es[hd * NN + i];
  float mx = -1e30f;
  for (int c = 0; c < 64; ++c) {
    ull_t w = mrow[c];
    float v = edh[c * 64 + lane];
    if ((w >> lane) & 1ull) mx = fmaxf(mx, v);
  }
#pragma unroll
  for (int off = 32; off; off >>= 1) mx = fmaxf(mx, __shfl_xor(mx, off, 64));
  float me = lrelu(esi + mx);
  float s = 0.f;
  for (int c = 0; c < 64; ++c) {
    ull_t w = mrow[c];
    float z = lrelu(esi + edh[c * 64 + lane]);
    float e = __expf(z - me);
    if ((w >> lane) & 1ull) s += e;
  }
#pragma unroll
  for (int off = 32; off; off >>= 1) s += __shfl_xor(s, off, 64);
  if (lane == 0) {
    mout[hd * NN + i] = me;
    linv[hd * NN + i] = (s > 0.f) ? 1.f / s : 0.f;
  }
}

// ---------------- barrier-free MFMA aggregation ----------------
// out[i, hd*F+f] = sum_j P(i,j) * hT[hd*F+f, j]
// wave = one 16-row i-tile x all F cols of one head. No LDS, no __syncthreads.
// A-frag: lane(q,nn) holds P[rowBase+nn][j0+s*32+q*8 .. +7], computed in-lane:
//   w = maskbit ? exp(lrelu(es_i+ed_j) + cn_i) : 0,  cn_i = log(li_i) - m_i.
// B-frag: lane(q,nn) holds hT[fBase+nn][j0+s*32+q*8 .. +7] -> one dwordx4 from L2.
// C/D: lane(q,nn) reg r -> out row rowBase+q*4+r, col fBase+nn (m89/m91 layout).
__device__ __forceinline__ float wgt(float su, float cn, unsigned byt, int bit) {
  float z = fmaxf(su, 0.2f * su);              // leaky-relu
  float e = __expf(z + cn);
  return (byt & (1u << bit)) ? e : 0.f;
}
__device__ __forceinline__ s16x8 build_a(float esi, float cn, unsigned byt,
                                         float4 ea, float4 eb) {
  float ev[8] = {ea.x, ea.y, ea.z, ea.w, eb.x, eb.y, eb.z, eb.w};
  union { s16x8 v; short2 p[4]; } A;
#pragma unroll
  for (int tp = 0; tp < 4; ++tp) {
    float w0 = wgt(esi + ev[2 * tp], cn, byt, 2 * tp);
    float w1 = wgt(esi + ev[2 * tp + 1], cn, byt, 2 * tp + 1);
    A.p[tp] = pkbf(w0, w1);
  }
  return A.v;
}

template <int F, typename TO>
__global__ __launch_bounds__(256, 1) void k_agg_mfma(
    const ushort_t* __restrict__ hT, const float* __restrict__ es,
    const float* __restrict__ ed, const float* __restrict__ mrowv,
    const float* __restrict__ linv, const ull_t* __restrict__ mask,
    TO* __restrict__ out) {
  constexpr int CT = F / 16;  // col-tiles per wave
  int t = threadIdx.x;
  int w = t >> 6, lane = t & 63;
  int q = lane >> 4, nn = lane & 15;
  int hd = blockIdx.y;
  int rowBase = blockIdx.x * 64 + w * 16;
  int ia = rowBase + nn;  // A-operand row this lane serves
  float esi = es[hd * NN + ia];
  float cn = __logf(linv[hd * NN + ia]) - mrowv[hd * NN + ia];  // li=0 -> -inf -> w=0
  const ull_t* mrk = mask + (size_t)ia * 64;
  const float* edh = ed + hd * NN;
  const ushort_t* hb = hT + (size_t)hd * F * NN;

  f32x4 acc[CT];
#pragma unroll
  for (int cc = 0; cc < CT; ++cc)
#pragma unroll
    for (int k = 0; k < 4; ++k) acc[cc][k] = 0.f;

  for (int jc = 0; jc < NN / 64; ++jc) {
    int j0 = jc * 64;
    // B fragments: direct global dwordx4 (L2-resident hT)
    uint4 bv[2][CT];
#pragma unroll
    for (int s = 0; s < 2; ++s)
#pragma unroll
      for (int cc = 0; cc < CT; ++cc)
        bv[s][cc] = *(const uint4*)&hb[(size_t)(cc * 16 + nn) * NN + j0 + s * 32 + q * 8];
    ull_t mk = mrk[jc];
    float4 e0 = *(const float4*)&edh[j0 + q * 8];
    float4 e1 = *(const float4*)&edh[j0 + q * 8 + 4];
    float4 e2 = *(const float4*)&edh[j0 + 32 + q * 8];
    float4 e3 = *(const float4*)&edh[j0 + 32 + q * 8 + 4];
    // A fragments: softmax weights computed in-lane (hides B-load latency)
    s16x8 a0 = build_a(esi, cn, (unsigned)(mk >> (q * 8)) & 0xffu, e0, e1);
    s16x8 a1 = build_a(esi, cn, (unsigned)(mk >> (32 + q * 8)) & 0xffu, e2, e3);
#pragma unroll
    for (int cc = 0; cc < CT; ++cc)
      acc[cc] = __builtin_amdgcn_mfma_f32_16x16x32_bf16(a0, as_s16x8(bv[0][cc]), acc[cc], 0, 0, 0);
#pragma unroll
    for (int cc = 0; cc < CT; ++cc)
      acc[cc] = __builtin_amdgcn_mfma_f32_16x16x32_bf16(a1, as_s16x8(bv[1][cc]), acc[cc], 0, 0, 0);
  }
  // epilogue: C/D layout col=nn, row=q*4+reg
#pragma unroll
  for (int cc = 0; cc < CT; ++cc)
#pragma unroll
    for (int reg = 0; reg < 4; ++reg) {
      int gi = rowBase + q * 4 + reg;
      sto(&out[(size_t)gi * (H4 * F) + hd * F + cc * 16 + nn], acc[cc][reg]);
    }
}

// ---------------- per-column mean / inv-std ----------------
__global__ __launch_bounds__(256) void k_colstats(const float* __restrict__ y,
                                                  float* __restrict__ stats, int C) {
  int c = blockIdx.x, tid = threadIdx.x;
  float s = 0.f, s2 = 0.f;
  for (int r = tid; r < NN; r += 256) {
    float v = y[(size_t)r * C + c];
    s += v;
    s2 += v * v;
  }
  __shared__ float sh[256], sh2[256];
  sh[tid] = s; sh2[tid] = s2;
  __syncthreads();
  for (int off = 128; off; off >>= 1) {
    if (tid < off) { sh[tid] += sh[tid + off]; sh2[tid] += sh2[tid + off]; }
    __syncthreads();
  }
  if (tid == 0) {
    float mean = sh[0] * (1.f / NN);
    float var = sh2[0] * (1.f / NN) - mean * mean;
    stats[c] = mean;
    stats[C + c] = rsqrtf(fmaxf(var, 0.f) + 1e-5f);
  }
}

// ---------------- BN + ELU ----------------
__global__ __launch_bounds__(256) void k_bn_elu(const float* __restrict__ y,
                                                const float* __restrict__ stats,
                                                const float* __restrict__ gamma,
                                                const float* __restrict__ beta,
                                                float* __restrict__ o, int C, int total) {
  int idx = blockIdx.x * 256 + threadIdx.x;
  if (idx >= total) return;
  int c = idx % C;
  float v = (y[idx] - stats[c]) * stats[C + c] * gamma[c] + beta[c];
  v = v > 0.f ? v : (__expf(v) - 1.f);
  o[idx] = v;
}

extern "C" void kernel_launch(void* const* d_in, const int* in_sizes, int n_in,
                              void* d_out, int out_size, void* d_ws, size_t ws_size,
                              hipStream_t stream) {
  (void)in_sizes; (void)n_in; (void)out_size; (void)ws_size;
  const float* x   = (const float*)d_in[0];
  const int*   adj = (const int*)d_in[1];
  const float* W1  = (const float*)d_in[2];
  const float* a1s = (const float*)d_in[3];
  const float* a1d = (const float*)d_in[4];
  const float* lw1 = (const float*)d_in[5];
  const float* lb1 = (const float*)d_in[6];
  const float* g1  = (const float*)d_in[7];
  const float* be1 = (const float*)d_in[8];
  const float* W2  = (const float*)d_in[9];
  const float* a2s = (const float*)d_in[10];
  const float* a2d = (const float*)d_in[11];
  const float* lw2 = (const float*)d_in[12];
  const float* lb2 = (const float*)d_in[13];
  const float* g2  = (const float*)d_in[14];
  const float* be2 = (const float*)d_in[15];
  float* out = (float*)d_out;

  // ---- workspace (peak 18.6 MB, proven layout), liveness-checked ----
  char* w = (char*)d_ws;
  const size_t MB = 1u << 20;
  ull_t* mask = (ull_t*)(w + 0);            // [0,2) whole session
  float*    h1  = (float*)(w + 2 * MB);     // [2,10) f32; dead after scores1/transpose1
  float*    y1  = (float*)(w + 2 * MB);     // [2,3)  overlay (gemm2 out; h1 dead)
  float*    x2  = (float*)(w + 3 * MB);     // [3,4)
  float*    h2  = (float*)(w + 4 * MB);     // [4,6)  dead after scores2/transpose2
  ushort_t* hT2 = (ushort_t*)(w + 6 * MB);  // [6,7)  bf16 h2^T
  float*    x3  = (float*)(w + 7 * MB);     // [7,9)
  float*    y2  = (float*)(w + 9 * MB);     // [9,9.25)
  ushort_t* hT1 = (ushort_t*)(w + 10 * MB); // [10,14) bf16 h1^T; dead after agg1
  bf16*     x1  = (bf16*)(w + 14 * MB);     // [14,18) bf16; dead after gemm2
  float* es1 = (float*)(w + 18 * MB);       // aux
  float* ed1 = es1 + 16384;
  float* m1  = ed1 + 16384;
  float* li1 = m1 + 16384;
  float* es2 = li1 + 16384;
  float* ed2 = es2 + 16384;
  float* m2  = ed2 + 16384;
  float* li2 = m2 + 16384;
  float* st1 = li2 + 16384;
  float* st2 = st1 + 256;

  k_mask<<<NN, 256, 0, stream>>>(adj, mask);

  // ---- layer 1 GAT ----
  k_gemm<float><<<dim3(8, 64), 256, 0, stream>>>(x, W1, nullptr, h1, NN, 512, 512);
  k_transpose<512><<<dim3(64, 32), 256, 0, stream>>>(h1, hT1);
  k_scores<128><<<(NN * H4) / 256, 256, 0, stream>>>(h1, a1s, a1d, es1, ed1);
  k_stats<<<NN, 256, 0, stream>>>(es1, ed1, mask, m1, li1);
  k_agg_mfma<128, bf16><<<dim3(64, 4), 256, 0, stream>>>(hT1, es1, ed1, m1, li1, mask, x1);

  // ---- linear + BN + ELU ----
  k_gemm<bf16><<<dim3(1, 64), 256, 0, stream>>>(x1, lw1, lb1, y1, NN, 512, 64);
  k_colstats<<<64, 256, 0, stream>>>(y1, st1, 64);
  k_bn_elu<<<(NN * 64) / 256, 256, 0, stream>>>(y1, st1, g1, be1, x2, 64, NN * 64);

  // ---- layer 2 GAT ----
  k_gemm<float><<<dim3(2, 64), 256, 0, stream>>>(x2, W2, nullptr, h2, NN, 64, 128);
  k_transpose<128><<<dim3(64, 8), 256, 0, stream>>>(h2, hT2);
  k_scores<32><<<(NN * H4) / 256, 256, 0, stream>>>(h2, a2s, a2d, es2, ed2);
  k_stats<<<NN, 256, 0, stream>>>(es2, ed2, mask, m2, li2);
  k_agg_mfma<32, float><<<dim3(64, 4), 256, 0, stream>>>(hT2, es2, ed2, m2, li2, mask, x3);

  // ---- final linear + BN + ELU ----
  k_gemm<float><<<dim3(1, 64), 256, 0, stream>>>(x3, lw2, lb2, y2, NN, 128, 16);
  k_colstats<<<16, 256, 0, stream>>>(y2, st2, 16);
  k_bn_elu<<<(NN * 16) / 256, 256, 0, stream>>>(y2, st2, g2, be2, out, 16, NN * 16);
}

// Round 6
// 471.591 us; speedup vs baseline: 1.1968x; 1.1968x over previous
//
#include <hip/hip_runtime.h>
#include <hip/hip_bf16.h>
#include <stdint.h>

#define NN 4096
#define H4 4

typedef __hip_bfloat16 bf16;
typedef unsigned short ushort_t;
typedef unsigned long long ull_t;
typedef __attribute__((ext_vector_type(4))) float f32x4;
typedef __attribute__((ext_vector_type(8))) short s16x8;

__device__ __forceinline__ float cvt(float v) { return v; }
__device__ __forceinline__ float cvt(bf16 v) { return __bfloat162float(v); }
__device__ __forceinline__ void sto(float* p, float v) { *p = v; }
__device__ __forceinline__ void sto(bf16* p, float v) { *p = __float2bfloat16(v); }
__device__ __forceinline__ ushort_t f2bf(float f) {
  unsigned u = __float_as_uint(f);
  return (ushort_t)((u + 0x7fff + ((u >> 16) & 1)) >> 16);
}
__device__ __forceinline__ short2 pkbf(float a, float b) {
  union { __hip_bfloat162 h; short2 s; } u;
  u.h = __float22bfloat162_rn(make_float2(a, b));
  return u.s;
}
__device__ __forceinline__ s16x8 as_s16x8(uint4 v) {
  union { uint4 u; s16x8 s; } c; c.u = v; return c.s;
}

// ---------------- adj -> 64-bit row masks ----------------
__global__ __launch_bounds__(256) void k_mask(const int* __restrict__ adj,
                                              ull_t* __restrict__ mask) {
  int row = blockIdx.x, tid = threadIdx.x;
  int lane = tid & 63, wv = tid >> 6;
  const int* arow = adj + (size_t)row * NN;
  for (int c = 0; c < NN; c += 256) {
    int col = c + wv * 64 + lane;
    ull_t b = __ballot(arow[col] != 0);
    if (lane == 0) mask[row * 64 + (c >> 6) + wv] = b;
  }
}

// ---------------- tiled GEMM: C[M,N] = A[M,K] @ B[K,N] (+bias) ----------------
template <typename TA>
__global__ __launch_bounds__(256) void k_gemm(const TA* __restrict__ A,
                                              const float* __restrict__ B,
                                              const float* __restrict__ bias,
                                              float* __restrict__ C, int M, int K, int Nc) {
  __shared__ float As[16][68];
  __shared__ float Bs[16][68];
  int tid = threadIdx.x;
  int tx = tid & 15, ty = tid >> 4;
  int mBase = blockIdx.y * 64, nBase = blockIdx.x * 64;
  float acc[4][4] = {};
  for (int k0 = 0; k0 < K; k0 += 16) {
#pragma unroll
    for (int l = 0; l < 4; ++l) {
      int idx = l * 256 + tid;
      int m = idx >> 4, k = idx & 15;
      As[k][m] = cvt(A[(size_t)(mBase + m) * K + (k0 + k)]);
    }
#pragma unroll
    for (int l = 0; l < 4; ++l) {
      int idx = l * 256 + tid;
      int k = idx >> 6, n = idx & 63;
      int gn = nBase + n;
      Bs[k][n] = (gn < Nc) ? B[(size_t)(k0 + k) * Nc + gn] : 0.f;
    }
    __syncthreads();
#pragma unroll
    for (int k = 0; k < 16; ++k) {
      float4 a = *(const float4*)&As[k][ty * 4];
      float4 b = *(const float4*)&Bs[k][tx * 4];
      float av[4] = {a.x, a.y, a.z, a.w};
      float bv[4] = {b.x, b.y, b.z, b.w};
#pragma unroll
      for (int r = 0; r < 4; ++r)
#pragma unroll
        for (int c = 0; c < 4; ++c) acc[r][c] += av[r] * bv[c];
    }
    __syncthreads();
  }
#pragma unroll
  for (int r = 0; r < 4; ++r) {
    int gm = mBase + ty * 4 + r;
#pragma unroll
    for (int c = 0; c < 4; ++c) {
      int gn = nBase + tx * 4 + c;
      if (gn < Nc) {
        float v = acc[r][c];
        if (bias) v += bias[gn];
        C[(size_t)gm * Nc + gn] = v;
      }
    }
  }
}

// ---------------- pack h[N][H4*F] f32 into MFMA B-fragment tiles (bf16) --------
// pk[(((hd*(F/16)+ct)*(NN/32)+ks)*64 + lane)*8 + u] = bf16(h[ks*32+q*8+u][hd*F+ct*16+nn])
// so the agg kernel's B-load is pk4[tile*64 + lane]: one fully-coalesced dwordx4/wave.
template <int F, int TB>
__global__ __launch_bounds__(TB) void k_pack(const float* __restrict__ h,
                                             ushort_t* __restrict__ pk) {
  constexpr int CTW = TB / 64;
  int t = threadIdx.x;
  int lane = t & 63, ctw = t >> 6;
  int q = lane >> 4, nn = lane & 15;
  int ks = blockIdx.x, hd = blockIdx.y;
#pragma unroll
  for (int ct = ctw; ct < F / 16; ct += CTW) {
    ushort_t v[8];
#pragma unroll
    for (int u = 0; u < 8; ++u)
      v[u] = f2bf(h[(size_t)(ks * 32 + q * 8 + u) * (H4 * F) + hd * F + ct * 16 + nn]);
    *(uint4*)&pk[((((size_t)hd * (F / 16) + ct) * (NN / 32) + ks) * 64 + lane) * 8] =
        *(uint4*)v;
  }
}

// ---------------- attention scores ----------------
template <int F>
__global__ __launch_bounds__(256) void k_scores(const float* __restrict__ h,
                                                const float* __restrict__ a_s,
                                                const float* __restrict__ a_d,
                                                float* __restrict__ es, float* __restrict__ ed) {
  int idx = blockIdx.x * 256 + threadIdx.x;
  if (idx >= NN * H4) return;
  int n = idx >> 2, hd = idx & 3;
  const float* hp = h + (size_t)n * (H4 * F) + hd * F;
  const float* sp = a_s + hd * F;
  const float* dp = a_d + hd * F;
  float ss = 0.f, sd = 0.f;
#pragma unroll 4
  for (int f = 0; f < F; ++f) {
    float v = hp[f];
    ss += v * sp[f];
    sd += v * dp[f];
  }
  es[hd * NN + n] = ss;
  ed[hd * NN + n] = sd;
}

// ---------------- masked-softmax stats (exact fp invariant: z <= me) --------
__global__ __launch_bounds__(256) void k_stats(const float* __restrict__ es,
                                               const float* __restrict__ ed,
                                               const ull_t* __restrict__ mask,
                                               float* __restrict__ mout, float* __restrict__ linv) {
  int i = blockIdx.x, tid = threadIdx.x;
  int hd = tid >> 6, lane = tid & 63;
  const ull_t* mrow = mask + (size_t)i * 64;
  const float* edh = ed + hd * NN;
  float esi = es[hd * NN + i];
  float mx = -1e30f;
  for (int c = 0; c < 64; ++c) {
    ull_t w = mrow[c];
    float v = edh[c * 64 + lane];
    if ((w >> lane) & 1ull) mx = fmaxf(mx, v);
  }
#pragma unroll
  for (int off = 32; off; off >>= 1) mx = fmaxf(mx, __shfl_xor(mx, off, 64));
  float z0 = esi + mx;
  float me = fmaxf(z0, 0.2f * z0);
  float s = 0.f;
  for (int c = 0; c < 64; ++c) {
    ull_t w = mrow[c];
    float zz = esi + edh[c * 64 + lane];
    float z = fmaxf(zz, 0.2f * zz);
    float e = __expf(z - me);
    if ((w >> lane) & 1ull) s += e;
  }
#pragma unroll
  for (int off = 32; off; off >>= 1) s += __shfl_xor(s, off, 64);
  if (lane == 0) {
    mout[hd * NN + i] = me;
    linv[hd * NN + i] = (s > 0.f) ? 1.f / s : 0.f;
  }
}

// ---------------- MFMA aggregation, packed-B + in-block j-split ----------------
// Wave = 32 rows (2 MFMA row-tiles) x all F cols of one head, over a j-quarter.
// Block = 4 waves = 4 j-quarters of the same rowgroup; barrier-free K-loop,
// 2-barrier LDS reduce at the end. A-frag (P weights) built in-lane:
//   w = maskbit ? exp(lrelu(es_i+ed_j) + cn_i) : 0, cn_i = log(li)-m_i.
__device__ __forceinline__ float wgt(float su, float cn, unsigned byt, int bit) {
  float z = fmaxf(su, 0.2f * su);
  float e = __expf(z + cn);
  return (byt & (1u << bit)) ? e : 0.f;
}
__device__ __forceinline__ s16x8 build_a(float esi, float cn, unsigned byt,
                                         float4 ea, float4 eb) {
  float ev[8] = {ea.x, ea.y, ea.z, ea.w, eb.x, eb.y, eb.z, eb.w};
  union { s16x8 v; short2 p[4]; } A;
#pragma unroll
  for (int tp = 0; tp < 4; ++tp) {
    float w0 = wgt(esi + ev[2 * tp], cn, byt, 2 * tp);
    float w1 = wgt(esi + ev[2 * tp + 1], cn, byt, 2 * tp + 1);
    A.p[tp] = pkbf(w0, w1);
  }
  return A.v;
}

template <int F, typename TO>
__global__ __launch_bounds__(256, 2) void k_agg_mfma(
    const uint4* __restrict__ pk, const float* __restrict__ es,
    const float* __restrict__ ed, const float* __restrict__ mrowv,
    const float* __restrict__ linv, const ull_t* __restrict__ mask,
    TO* __restrict__ out) {
  constexpr int CT = F / 16;
  __shared__ float red[2 * 32 * F];
  int t = threadIdx.x;
  int w = t >> 6, lane = t & 63;
  int q = lane >> 4, nn = lane & 15;
  int hd = blockIdx.y;
  int rowBase = blockIdx.x * 32;
  int jBase = w * (NN / 4);  // this wave's j-quarter
  int ia0 = rowBase + nn, ia1 = rowBase + 16 + nn;
  float es0 = es[hd * NN + ia0];
  float cn0 = __logf(linv[hd * NN + ia0]) - mrowv[hd * NN + ia0];
  float es1 = es[hd * NN + ia1];
  float cn1 = __logf(linv[hd * NN + ia1]) - mrowv[hd * NN + ia1];
  const ull_t* mk0p = mask + (size_t)ia0 * 64;
  const ull_t* mk1p = mask + (size_t)ia1 * 64;
  const float* edh = ed + hd * NN;

  f32x4 acc[2][CT];
#pragma unroll
  for (int rt = 0; rt < 2; ++rt)
#pragma unroll
    for (int cc = 0; cc < CT; ++cc)
#pragma unroll
      for (int k = 0; k < 4; ++k) acc[rt][cc][k] = 0.f;

  for (int jc = 0; jc < NN / 4 / 64; ++jc) {
    int j0 = jBase + jc * 64;
    int ks0 = j0 >> 5;
    // B fragments: coalesced dwordx4 from packed tiles (L2-resident)
    uint4 bv[2][CT];
#pragma unroll
    for (int s = 0; s < 2; ++s)
#pragma unroll
      for (int cc = 0; cc < CT; ++cc)
        bv[s][cc] = pk[(size_t)((hd * CT + cc) * (NN / 32) + ks0 + s) * 64 + lane];
    ull_t mk0 = mk0p[j0 >> 6], mk1 = mk1p[j0 >> 6];
    float4 e0 = *(const float4*)&edh[j0 + q * 8];
    float4 e1 = *(const float4*)&edh[j0 + q * 8 + 4];
    float4 e2 = *(const float4*)&edh[j0 + 32 + q * 8];
    float4 e3 = *(const float4*)&edh[j0 + 32 + q * 8 + 4];
    s16x8 a00 = build_a(es0, cn0, (unsigned)(mk0 >> (q * 8)) & 0xffu, e0, e1);
    s16x8 a01 = build_a(es0, cn0, (unsigned)(mk0 >> (32 + q * 8)) & 0xffu, e2, e3);
    s16x8 a10 = build_a(es1, cn1, (unsigned)(mk1 >> (q * 8)) & 0xffu, e0, e1);
    s16x8 a11 = build_a(es1, cn1, (unsigned)(mk1 >> (32 + q * 8)) & 0xffu, e2, e3);
#pragma unroll
    for (int cc = 0; cc < CT; ++cc)
      acc[0][cc] = __builtin_amdgcn_mfma_f32_16x16x32_bf16(a00, as_s16x8(bv[0][cc]), acc[0][cc], 0, 0, 0);
#pragma unroll
    for (int cc = 0; cc < CT; ++cc)
      acc[0][cc] = __builtin_amdgcn_mfma_f32_16x16x32_bf16(a01, as_s16x8(bv[1][cc]), acc[0][cc], 0, 0, 0);
#pragma unroll
    for (int cc = 0; cc < CT; ++cc)
      acc[1][cc] = __builtin_amdgcn_mfma_f32_16x16x32_bf16(a10, as_s16x8(bv[0][cc]), acc[1][cc], 0, 0, 0);
#pragma unroll
    for (int cc = 0; cc < CT; ++cc)
      acc[1][cc] = __builtin_amdgcn_mfma_f32_16x16x32_bf16(a11, as_s16x8(bv[1][cc]), acc[1][cc], 0, 0, 0);
  }

  // ---- cross-wave reduce: pairs (0,1)->region0, (2,3)->region1, then 0+=2 ----
#define IDX(rt, cc, reg) ((rt * 16 + q * 4 + reg) * F + cc * 16 + nn)
  if (w == 1 || w == 3) {
    int base = (w >> 1) * 32 * F;
#pragma unroll
    for (int rt = 0; rt < 2; ++rt)
#pragma unroll
      for (int cc = 0; cc < CT; ++cc)
#pragma unroll
        for (int reg = 0; reg < 4; ++reg) red[base + IDX(rt, cc, reg)] = acc[rt][cc][reg];
  }
  __syncthreads();
  if (w == 0 || w == 2) {
    int base = (w >> 1) * 32 * F;
#pragma unroll
    for (int rt = 0; rt < 2; ++rt)
#pragma unroll
      for (int cc = 0; cc < CT; ++cc)
#pragma unroll
        for (int reg = 0; reg < 4; ++reg) acc[rt][cc][reg] += red[base + IDX(rt, cc, reg)];
  }
  if (w == 2) {
#pragma unroll
    for (int rt = 0; rt < 2; ++rt)
#pragma unroll
      for (int cc = 0; cc < CT; ++cc)
#pragma unroll
        for (int reg = 0; reg < 4; ++reg) red[32 * F + IDX(rt, cc, reg)] = acc[rt][cc][reg];
  }
  __syncthreads();
  if (w == 0) {
#pragma unroll
    for (int rt = 0; rt < 2; ++rt)
#pragma unroll
      for (int cc = 0; cc < CT; ++cc)
#pragma unroll
        for (int reg = 0; reg < 4; ++reg) {
          float v = acc[rt][cc][reg] + red[32 * F + IDX(rt, cc, reg)];
          int gi = rowBase + rt * 16 + q * 4 + reg;
          sto(&out[(size_t)gi * (H4 * F) + hd * F + cc * 16 + nn], v);
        }
  }
#undef IDX
}

// ---------------- per-column mean / inv-std ----------------
__global__ __launch_bounds__(256) void k_colstats(const float* __restrict__ y,
                                                  float* __restrict__ stats, int C) {
  int c = blockIdx.x, tid = threadIdx.x;
  float s = 0.f, s2 = 0.f;
  for (int r = tid; r < NN; r += 256) {
    float v = y[(size_t)r * C + c];
    s += v;
    s2 += v * v;
  }
  __shared__ float sh[256], sh2[256];
  sh[tid] = s; sh2[tid] = s2;
  __syncthreads();
  for (int off = 128; off; off >>= 1) {
    if (tid < off) { sh[tid] += sh[tid + off]; sh2[tid] += sh2[tid + off]; }
    __syncthreads();
  }
  if (tid == 0) {
    float mean = sh[0] * (1.f / NN);
    float var = sh2[0] * (1.f / NN) - mean * mean;
    stats[c] = mean;
    stats[C + c] = rsqrtf(fmaxf(var, 0.f) + 1e-5f);
  }
}

// ---------------- BN + ELU ----------------
__global__ __launch_bounds__(256) void k_bn_elu(const float* __restrict__ y,
                                                const float* __restrict__ stats,
                                                const float* __restrict__ gamma,
                                                const float* __restrict__ beta,
                                                float* __restrict__ o, int C, int total) {
  int idx = blockIdx.x * 256 + threadIdx.x;
  if (idx >= total) return;
  int c = idx % C;
  float v = (y[idx] - stats[c]) * stats[C + c] * gamma[c] + beta[c];
  v = v > 0.f ? v : (__expf(v) - 1.f);
  o[idx] = v;
}

extern "C" void kernel_launch(void* const* d_in, const int* in_sizes, int n_in,
                              void* d_out, int out_size, void* d_ws, size_t ws_size,
                              hipStream_t stream) {
  (void)in_sizes; (void)n_in; (void)out_size; (void)ws_size;
  const float* x   = (const float*)d_in[0];
  const int*   adj = (const int*)d_in[1];
  const float* W1  = (const float*)d_in[2];
  const float* a1s = (const float*)d_in[3];
  const float* a1d = (const float*)d_in[4];
  const float* lw1 = (const float*)d_in[5];
  const float* lb1 = (const float*)d_in[6];
  const float* g1  = (const float*)d_in[7];
  const float* be1 = (const float*)d_in[8];
  const float* W2  = (const float*)d_in[9];
  const float* a2s = (const float*)d_in[10];
  const float* a2d = (const float*)d_in[11];
  const float* lw2 = (const float*)d_in[12];
  const float* lb2 = (const float*)d_in[13];
  const float* g2  = (const float*)d_in[14];
  const float* be2 = (const float*)d_in[15];
  float* out = (float*)d_out;

  // ---- workspace (peak 18.6 MB, proven), liveness-checked overlays ----
  char* w = (char*)d_ws;
  const size_t MB = 1u << 20;
  ull_t* mask = (ull_t*)(w + 0);            // [0,2) whole session
  float*    h1  = (float*)(w + 2 * MB);     // [2,10) f32; dead after pack1/scores1
  float*    y1  = (float*)(w + 2 * MB);     // [2,3)  overlay (gemm2 out; h1 dead)
  float*    x2  = (float*)(w + 3 * MB);     // [3,4)
  float*    h2  = (float*)(w + 4 * MB);     // [4,6)  dead after pack2/scores2
  ushort_t* pk2 = (ushort_t*)(w + 6 * MB);  // [6,7)  packed B tiles layer2 (1MB)
  float*    x3  = (float*)(w + 7 * MB);     // [7,9)
  float*    y2  = (float*)(w + 9 * MB);     // [9,9.25)
  ushort_t* pk1 = (ushort_t*)(w + 10 * MB); // [10,14) packed B tiles layer1 (4MB)
  bf16*     x1  = (bf16*)(w + 14 * MB);     // [14,18) bf16; dead after gemm2
  float* es1 = (float*)(w + 18 * MB);       // aux
  float* ed1 = es1 + 16384;
  float* m1  = ed1 + 16384;
  float* li1 = m1 + 16384;
  float* es2 = li1 + 16384;
  float* ed2 = es2 + 16384;
  float* m2  = ed2 + 16384;
  float* li2 = m2 + 16384;
  float* st1 = li2 + 16384;
  float* st2 = st1 + 256;

  k_mask<<<NN, 256, 0, stream>>>(adj, mask);

  // ---- layer 1 GAT ----
  k_gemm<float><<<dim3(8, 64), 256, 0, stream>>>(x, W1, nullptr, h1, NN, 512, 512);
  k_pack<128, 256><<<dim3(NN / 32, H4), 256, 0, stream>>>(h1, pk1);
  k_scores<128><<<(NN * H4) / 256, 256, 0, stream>>>(h1, a1s, a1d, es1, ed1);
  k_stats<<<NN, 256, 0, stream>>>(es1, ed1, mask, m1, li1);
  k_agg_mfma<128, bf16><<<dim3(128, H4), 256, 0, stream>>>((const uint4*)pk1, es1, ed1, m1,
                                                           li1, mask, x1);

  // ---- linear + BN + ELU ----
  k_gemm<bf16><<<dim3(1, 64), 256, 0, stream>>>(x1, lw1, lb1, y1, NN, 512, 64);
  k_colstats<<<64, 256, 0, stream>>>(y1, st1, 64);
  k_bn_elu<<<(NN * 64) / 256, 256, 0, stream>>>(y1, st1, g1, be1, x2, 64, NN * 64);

  // ---- layer 2 GAT ----
  k_gemm<float><<<dim3(2, 64), 256, 0, stream>>>(x2, W2, nullptr, h2, NN, 64, 128);
  k_pack<32, 128><<<dim3(NN / 32, H4), 128, 0, stream>>>(h2, pk2);
  k_scores<32><<<(NN * H4) / 256, 256, 0, stream>>>(h2, a2s, a2d, es2, ed2);
  k_stats<<<NN, 256, 0, stream>>>(es2, ed2, mask, m2, li2);
  k_agg_mfma<32, float><<<dim3(128, H4), 256, 0, stream>>>((const uint4*)pk2, es2, ed2, m2,
                                                           li2, mask, x3);

  // ---- final linear + BN + ELU ----
  k_gemm<float><<<dim3(1, 64), 256, 0, stream>>>(x3, lw2, lb2, y2, NN, 128, 16);
  k_colstats<<<16, 256, 0, stream>>>(y2, st2, 16);
  k_bn_elu<<<(NN * 16) / 256, 256, 0, stream>>>(y2, st2, g2, be2, out, 16, NN * 16);
}

// Round 8
// 431.601 us; speedup vs baseline: 1.3077x; 1.0927x over previous
//
#include <hip/hip_runtime.h>
#include <hip/hip_bf16.h>
#include <stdint.h>

#define NN 4096
#define H4 4

typedef __hip_bfloat16 bf16;
typedef unsigned short ushort_t;
typedef unsigned long long ull_t;
typedef __attribute__((ext_vector_type(4))) float f32x4;
typedef __attribute__((ext_vector_type(8))) short s16x8;

__device__ __forceinline__ float cvt(float v) { return v; }
__device__ __forceinline__ float cvt(bf16 v) { return __bfloat162float(v); }
__device__ __forceinline__ void sto(float* p, float v) { *p = v; }
__device__ __forceinline__ void sto(bf16* p, float v) { *p = __float2bfloat16(v); }
__device__ __forceinline__ ushort_t f2bf(float f) {
  unsigned u = __float_as_uint(f);
  return (ushort_t)((u + 0x7fff + ((u >> 16) & 1)) >> 16);
}
__device__ __forceinline__ float bf2f(ushort_t h) {
  return __uint_as_float((unsigned)h << 16);
}
__device__ __forceinline__ short2 pkbf(float a, float b) {
  union { __hip_bfloat162 h; short2 s; } u;
  u.h = __float22bfloat162_rn(make_float2(a, b));
  return u.s;
}
__device__ __forceinline__ s16x8 as_s16x8(uint4 v) {
  union { uint4 u; s16x8 s; } c; c.u = v; return c.s;
}

// ---------------- adj -> 64-bit row masks ----------------
__global__ __launch_bounds__(256) void k_mask(const int* __restrict__ adj,
                                              ull_t* __restrict__ mask) {
  int row = blockIdx.x, tid = threadIdx.x;
  int lane = tid & 63, wv = tid >> 6;
  const int* arow = adj + (size_t)row * NN;
  for (int c = 0; c < NN; c += 256) {
    int col = c + wv * 64 + lane;
    ull_t b = __ballot(arow[col] != 0);
    if (lane == 0) mask[row * 64 + (c >> 6) + wv] = b;
  }
}

// ---------------- tiled GEMM (fp32 VALU, used for small GEMMs) ----------------
template <typename TA>
__global__ __launch_bounds__(256) void k_gemm(const TA* __restrict__ A,
                                              const float* __restrict__ B,
                                              const float* __restrict__ bias,
                                              float* __restrict__ C, int M, int K, int Nc) {
  __shared__ float As[16][68];
  __shared__ float Bs[16][68];
  int tid = threadIdx.x;
  int tx = tid & 15, ty = tid >> 4;
  int mBase = blockIdx.y * 64, nBase = blockIdx.x * 64;
  float acc[4][4] = {};
  for (int k0 = 0; k0 < K; k0 += 16) {
#pragma unroll
    for (int l = 0; l < 4; ++l) {
      int idx = l * 256 + tid;
      int m = idx >> 4, k = idx & 15;
      As[k][m] = cvt(A[(size_t)(mBase + m) * K + (k0 + k)]);
    }
#pragma unroll
    for (int l = 0; l < 4; ++l) {
      int idx = l * 256 + tid;
      int k = idx >> 6, n = idx & 63;
      int gn = nBase + n;
      Bs[k][n] = (gn < Nc) ? B[(size_t)(k0 + k) * Nc + gn] : 0.f;
    }
    __syncthreads();
#pragma unroll
    for (int k = 0; k < 16; ++k) {
      float4 a = *(const float4*)&As[k][ty * 4];
      float4 b = *(const float4*)&Bs[k][tx * 4];
      float av[4] = {a.x, a.y, a.z, a.w};
      float bv[4] = {b.x, b.y, b.z, b.w};
#pragma unroll
      for (int r = 0; r < 4; ++r)
#pragma unroll
        for (int c = 0; c < 4; ++c) acc[r][c] += av[r] * bv[c];
    }
    __syncthreads();
  }
#pragma unroll
  for (int r = 0; r < 4; ++r) {
    int gm = mBase + ty * 4 + r;
#pragma unroll
    for (int c = 0; c < 4; ++c) {
      int gn = nBase + tx * 4 + c;
      if (gn < Nc) {
        float v = acc[r][c];
        if (bias) v += bias[gn];
        C[(size_t)gm * Nc + gn] = v;
      }
    }
  }
}

// ---------------- pack x[4096][512] into MFMA A-fragment tiles, bf16 hi/lo --------
// pkA[plane][((mt*16+ks)*64+lane)*8+u] = bf16_part(x[mt*16+nn][ks*32+q*8+u])
#define APLANE (4096 * 512)
__global__ __launch_bounds__(256) void k_packA(const float* __restrict__ x,
                                               ushort_t* __restrict__ pkA) {
  int t = threadIdx.x;
  int w = t >> 6, lane = t & 63;
  int q = lane >> 4, nn = lane & 15;
  int tau = blockIdx.x * 4 + w;  // 4096 tiles: mt in [0,256), ks in [0,16)
  int mt = tau >> 4, ks = tau & 15;
  const float* src = &x[(size_t)(mt * 16 + nn) * 512 + ks * 32 + q * 8];
  float4 v0 = *(const float4*)src;
  float4 v1 = *(const float4*)(src + 4);
  float vv[8] = {v0.x, v0.y, v0.z, v0.w, v1.x, v1.y, v1.z, v1.w};
  ushort_t hi[8], lo[8];
#pragma unroll
  for (int u = 0; u < 8; ++u) {
    hi[u] = f2bf(vv[u]);
    lo[u] = f2bf(vv[u] - bf2f(hi[u]));
  }
  size_t idx = ((size_t)(mt * 16 + ks) * 64 + lane) * 8;
  *(uint4*)&pkA[idx] = *(uint4*)hi;
  *(uint4*)&pkA[APLANE + idx] = *(uint4*)lo;
}

// ---------------- pack W1[512][512] into MFMA B-fragment tiles, bf16 hi/lo --------
// pkW[plane][((ct*16+ks)*64+lane)*8+u] = bf16_part(W[ks*32+q*8+u][ct*16+nn])
#define WPLANE (512 * 512)
__global__ __launch_bounds__(256) void k_packW(const float* __restrict__ W,
                                               ushort_t* __restrict__ pkW) {
  int t = threadIdx.x;
  int w = t >> 6, lane = t & 63;
  int q = lane >> 4, nn = lane & 15;
  int tau = blockIdx.x * 4 + w;  // 512 tiles: ct in [0,32), ks in [0,16)
  int ct = tau >> 4, ks = tau & 15;
  ushort_t hi[8], lo[8];
#pragma unroll
  for (int u = 0; u < 8; ++u) {
    float v = W[(size_t)(ks * 32 + q * 8 + u) * 512 + ct * 16 + nn];
    hi[u] = f2bf(v);
    lo[u] = f2bf(v - bf2f(hi[u]));
  }
  size_t idx = ((size_t)(ct * 16 + ks) * 64 + lane) * 8;
  *(uint4*)&pkW[idx] = *(uint4*)hi;
  *(uint4*)&pkW[WPLANE + idx] = *(uint4*)lo;
}

// ---------------- h1 = x @ W1 via split-bf16 MFMA (hi*hi + hi*lo + lo*hi) --------
// Wave = 32 rows x 64 cols; block = 4 waves (64x128); grid 64x4. Register-direct,
// barrier-free; every load a coalesced dwordx4 from packed tiles (L2-resident).
__global__ __launch_bounds__(256, 1) void k_mm1(const uint4* __restrict__ pkA,
                                                const uint4* __restrict__ pkW,
                                                float* __restrict__ h1) {
  constexpr int APL4 = APLANE / 8;
  constexpr int WPL4 = WPLANE / 8;
  int t = threadIdx.x;
  int w = t >> 6, lane = t & 63;
  int q = lane >> 4, nn = lane & 15;
  int mt0 = blockIdx.x * 4 + (w & 1) * 2;   // two row-tiles: mt0, mt0+1
  int ct0 = blockIdx.y * 8 + (w >> 1) * 4;  // four col-tiles
  f32x4 acc[2][4];
#pragma unroll
  for (int rt = 0; rt < 2; ++rt)
#pragma unroll
    for (int c = 0; c < 4; ++c)
#pragma unroll
      for (int k = 0; k < 4; ++k) acc[rt][c][k] = 0.f;
#pragma unroll
  for (int ks = 0; ks < 16; ++ks) {
    int ia0 = (mt0 * 16 + ks) * 64 + lane;
    int ia1 = ((mt0 + 1) * 16 + ks) * 64 + lane;
    uint4 ah0 = pkA[ia0], ah1 = pkA[ia1];
    uint4 al0 = pkA[APL4 + ia0], al1 = pkA[APL4 + ia1];
    uint4 bh[4], bl[4];
#pragma unroll
    for (int c = 0; c < 4; ++c) {
      int ib = ((ct0 + c) * 16 + ks) * 64 + lane;
      bh[c] = pkW[ib];
      bl[c] = pkW[WPL4 + ib];
    }
#pragma unroll
    for (int c = 0; c < 4; ++c) {
      acc[0][c] = __builtin_amdgcn_mfma_f32_16x16x32_bf16(as_s16x8(ah0), as_s16x8(bh[c]), acc[0][c], 0, 0, 0);
      acc[0][c] = __builtin_amdgcn_mfma_f32_16x16x32_bf16(as_s16x8(ah0), as_s16x8(bl[c]), acc[0][c], 0, 0, 0);
      acc[0][c] = __builtin_amdgcn_mfma_f32_16x16x32_bf16(as_s16x8(al0), as_s16x8(bh[c]), acc[0][c], 0, 0, 0);
      acc[1][c] = __builtin_amdgcn_mfma_f32_16x16x32_bf16(as_s16x8(ah1), as_s16x8(bh[c]), acc[1][c], 0, 0, 0);
      acc[1][c] = __builtin_amdgcn_mfma_f32_16x16x32_bf16(as_s16x8(ah1), as_s16x8(bl[c]), acc[1][c], 0, 0, 0);
      acc[1][c] = __builtin_amdgcn_mfma_f32_16x16x32_bf16(as_s16x8(al1), as_s16x8(bh[c]), acc[1][c], 0, 0, 0);
    }
  }
  int rowB = blockIdx.x * 64 + (w & 1) * 32;
#pragma unroll
  for (int rt = 0; rt < 2; ++rt)
#pragma unroll
    for (int c = 0; c < 4; ++c)
#pragma unroll
      for (int reg = 0; reg < 4; ++reg) {
        int gi = rowB + rt * 16 + q * 4 + reg;
        h1[(size_t)gi * 512 + (ct0 + c) * 16 + nn] = acc[rt][c][reg];
      }
}

// ---------------- pack h[N][H4*F] f32 into MFMA B-fragment tiles (bf16) --------
template <int F, int TB>
__global__ __launch_bounds__(TB) void k_pack(const float* __restrict__ h,
                                             ushort_t* __restrict__ pk) {
  constexpr int CTW = TB / 64;
  int t = threadIdx.x;
  int lane = t & 63, ctw = t >> 6;
  int q = lane >> 4, nn = lane & 15;
  int ks = blockIdx.x, hd = blockIdx.y;
#pragma unroll
  for (int ct = ctw; ct < F / 16; ct += CTW) {
    ushort_t v[8];
#pragma unroll
    for (int u = 0; u < 8; ++u)
      v[u] = f2bf(h[(size_t)(ks * 32 + q * 8 + u) * (H4 * F) + hd * F + ct * 16 + nn]);
    *(uint4*)&pk[((((size_t)hd * (F / 16) + ct) * (NN / 32) + ks) * 64 + lane) * 8] =
        *(uint4*)v;
  }
}

// ---------------- attention scores ----------------
template <int F>
__global__ __launch_bounds__(256) void k_scores(const float* __restrict__ h,
                                                const float* __restrict__ a_s,
                                                const float* __restrict__ a_d,
                                                float* __restrict__ es, float* __restrict__ ed) {
  int idx = blockIdx.x * 256 + threadIdx.x;
  if (idx >= NN * H4) return;
  int n = idx >> 2, hd = idx & 3;
  const float* hp = h + (size_t)n * (H4 * F) + hd * F;
  const float* sp = a_s + hd * F;
  const float* dp = a_d + hd * F;
  float ss = 0.f, sd = 0.f;
#pragma unroll 4
  for (int f = 0; f < F; ++f) {
    float v = hp[f];
    ss += v * sp[f];
    sd += v * dp[f];
  }
  es[hd * NN + n] = ss;
  ed[hd * NN + n] = sd;
}

// ---------------- masked-softmax stats (exact fp invariant: z <= me) --------
__global__ __launch_bounds__(256) void k_stats(const float* __restrict__ es,
                                               const float* __restrict__ ed,
                                               const ull_t* __restrict__ mask,
                                               float* __restrict__ mout, float* __restrict__ linv) {
  int i = blockIdx.x, tid = threadIdx.x;
  int hd = tid >> 6, lane = tid & 63;
  const ull_t* mrow = mask + (size_t)i * 64;
  const float* edh = ed + hd * NN;
  float esi = es[hd * NN + i];
  float mx = -1e30f;
  for (int c = 0; c < 64; ++c) {
    ull_t w = mrow[c];
    float v = edh[c * 64 + lane];
    if ((w >> lane) & 1ull) mx = fmaxf(mx, v);
  }
#pragma unroll
  for (int off = 32; off; off >>= 1) mx = fmaxf(mx, __shfl_xor(mx, off, 64));
  float z0 = esi + mx;
  float me = fmaxf(z0, 0.2f * z0);
  float s = 0.f;
  for (int c = 0; c < 64; ++c) {
    ull_t w = mrow[c];
    float zz = esi + edh[c * 64 + lane];
    float z = fmaxf(zz, 0.2f * zz);
    float e = __expf(z - me);
    if ((w >> lane) & 1ull) s += e;
  }
#pragma unroll
  for (int off = 32; off; off >>= 1) s += __shfl_xor(s, off, 64);
  if (lane == 0) {
    mout[hd * NN + i] = me;
    linv[hd * NN + i] = (s > 0.f) ? 1.f / s : 0.f;
  }
}

// ---------------- MFMA aggregation, packed-B + in-block j-split ----------------
__device__ __forceinline__ float wgt(float su, float cn, unsigned byt, int bit) {
  float z = fmaxf(su, 0.2f * su);
  float e = __expf(z + cn);
  return (byt & (1u << bit)) ? e : 0.f;
}
__device__ __forceinline__ s16x8 build_a(float esi, float cn, unsigned byt,
                                         float4 ea, float4 eb) {
  float ev[8] = {ea.x, ea.y, ea.z, ea.w, eb.x, eb.y, eb.z, eb.w};
  union { s16x8 v; short2 p[4]; } A;
#pragma unroll
  for (int tp = 0; tp < 4; ++tp) {
    float w0 = wgt(esi + ev[2 * tp], cn, byt, 2 * tp);
    float w1 = wgt(esi + ev[2 * tp + 1], cn, byt, 2 * tp + 1);
    A.p[tp] = pkbf(w0, w1);
  }
  return A.v;
}

template <int F, typename TO>
__global__ __launch_bounds__(256, 2) void k_agg_mfma(
    const uint4* __restrict__ pk, const float* __restrict__ es,
    const float* __restrict__ ed, const float* __restrict__ mrowv,
    const float* __restrict__ linv, const ull_t* __restrict__ mask,
    TO* __restrict__ out) {
  constexpr int CT = F / 16;
  __shared__ float red[2 * 32 * F];
  int t = threadIdx.x;
  int w = t >> 6, lane = t & 63;
  int q = lane >> 4, nn = lane & 15;
  int hd = blockIdx.y;
  int rowBase = blockIdx.x * 32;
  int jBase = w * (NN / 4);
  int ia0 = rowBase + nn, ia1 = rowBase + 16 + nn;
  float es0 = es[hd * NN + ia0];
  float cn0 = __logf(linv[hd * NN + ia0]) - mrowv[hd * NN + ia0];
  float es1 = es[hd * NN + ia1];
  float cn1 = __logf(linv[hd * NN + ia1]) - mrowv[hd * NN + ia1];
  const ull_t* mk0p = mask + (size_t)ia0 * 64;
  const ull_t* mk1p = mask + (size_t)ia1 * 64;
  const float* edh = ed + hd * NN;

  f32x4 acc[2][CT];
#pragma unroll
  for (int rt = 0; rt < 2; ++rt)
#pragma unroll
    for (int cc = 0; cc < CT; ++cc)
#pragma unroll
      for (int k = 0; k < 4; ++k) acc[rt][cc][k] = 0.f;

  for (int jc = 0; jc < NN / 4 / 64; ++jc) {
    int j0 = jBase + jc * 64;
    int ks0 = j0 >> 5;
    uint4 bv[2][CT];
#pragma unroll
    for (int s = 0; s < 2; ++s)
#pragma unroll
      for (int cc = 0; cc < CT; ++cc)
        bv[s][cc] = pk[(size_t)((hd * CT + cc) * (NN / 32) + ks0 + s) * 64 + lane];
    ull_t mk0 = mk0p[j0 >> 6], mk1 = mk1p[j0 >> 6];
    float4 e0 = *(const float4*)&edh[j0 + q * 8];
    float4 e1 = *(const float4*)&edh[j0 + q * 8 + 4];
    float4 e2 = *(const float4*)&edh[j0 + 32 + q * 8];
    float4 e3 = *(const float4*)&edh[j0 + 32 + q * 8 + 4];
    s16x8 a00 = build_a(es0, cn0, (unsigned)(mk0 >> (q * 8)) & 0xffu, e0, e1);
    s16x8 a01 = build_a(es0, cn0, (unsigned)(mk0 >> (32 + q * 8)) & 0xffu, e2, e3);
    s16x8 a10 = build_a(es1, cn1, (unsigned)(mk1 >> (q * 8)) & 0xffu, e0, e1);
    s16x8 a11 = build_a(es1, cn1, (unsigned)(mk1 >> (32 + q * 8)) & 0xffu, e2, e3);
#pragma unroll
    for (int cc = 0; cc < CT; ++cc)
      acc[0][cc] = __builtin_amdgcn_mfma_f32_16x16x32_bf16(a00, as_s16x8(bv[0][cc]), acc[0][cc], 0, 0, 0);
#pragma unroll
    for (int cc = 0; cc < CT; ++cc)
      acc[0][cc] = __builtin_amdgcn_mfma_f32_16x16x32_bf16(a01, as_s16x8(bv[1][cc]), acc[0][cc], 0, 0, 0);
#pragma unroll
    for (int cc = 0; cc < CT; ++cc)
      acc[1][cc] = __builtin_amdgcn_mfma_f32_16x16x32_bf16(a10, as_s16x8(bv[0][cc]), acc[1][cc], 0, 0, 0);
#pragma unroll
    for (int cc = 0; cc < CT; ++cc)
      acc[1][cc] = __builtin_amdgcn_mfma_f32_16x16x32_bf16(a11, as_s16x8(bv[1][cc]), acc[1][cc], 0, 0, 0);
  }

#define IDX(rt, cc, reg) ((rt * 16 + q * 4 + reg) * F + cc * 16 + nn)
  if (w == 1 || w == 3) {
    int base = (w >> 1) * 32 * F;
#pragma unroll
    for (int rt = 0; rt < 2; ++rt)
#pragma unroll
      for (int cc = 0; cc < CT; ++cc)
#pragma unroll
        for (int reg = 0; reg < 4; ++reg) red[base + IDX(rt, cc, reg)] = acc[rt][cc][reg];
  }
  __syncthreads();
  if (w == 0 || w == 2) {
    int base = (w >> 1) * 32 * F;
#pragma unroll
    for (int rt = 0; rt < 2; ++rt)
#pragma unroll
      for (int cc = 0; cc < CT; ++cc)
#pragma unroll
        for (int reg = 0; reg < 4; ++reg) acc[rt][cc][reg] += red[base + IDX(rt, cc, reg)];
  }
  if (w == 2) {
#pragma unroll
    for (int rt = 0; rt < 2; ++rt)
#pragma unroll
      for (int cc = 0; cc < CT; ++cc)
#pragma unroll
        for (int reg = 0; reg < 4; ++reg) red[32 * F + IDX(rt, cc, reg)] = acc[rt][cc][reg];
  }
  __syncthreads();
  if (w == 0) {
#pragma unroll
    for (int rt = 0; rt < 2; ++rt)
#pragma unroll
      for (int cc = 0; cc < CT; ++cc)
#pragma unroll
        for (int reg = 0; reg < 4; ++reg) {
          float v = acc[rt][cc][reg] + red[32 * F + IDX(rt, cc, reg)];
          int gi = rowBase + rt * 16 + q * 4 + reg;
          sto(&out[(size_t)gi * (H4 * F) + hd * F + cc * 16 + nn], v);
        }
  }
#undef IDX
}

// ---------------- per-column mean / inv-std ----------------
__global__ __launch_bounds__(256) void k_colstats(const float* __restrict__ y,
                                                  float* __restrict__ stats, int C) {
  int c = blockIdx.x, tid = threadIdx.x;
  float s = 0.f, s2 = 0.f;
  for (int r = tid; r < NN; r += 256) {
    float v = y[(size_t)r * C + c];
    s += v;
    s2 += v * v;
  }
  __shared__ float sh[256], sh2[256];
  sh[tid] = s; sh2[tid] = s2;
  __syncthreads();
  for (int off = 128; off; off >>= 1) {
    if (tid < off) { sh[tid] += sh[tid + off]; sh2[tid] += sh2[tid + off]; }
    __syncthreads();
  }
  if (tid == 0) {
    float mean = sh[0] * (1.f / NN);
    float var = sh2[0] * (1.f / NN) - mean * mean;
    stats[c] = mean;
    stats[C + c] = rsqrtf(fmaxf(var, 0.f) + 1e-5f);
  }
}

// ---------------- BN + ELU ----------------
__global__ __launch_bounds__(256) void k_bn_elu(const float* __restrict__ y,
                                                const float* __restrict__ stats,
                                                const float* __restrict__ gamma,
                                                const float* __restrict__ beta,
                                                float* __restrict__ o, int C, int total) {
  int idx = blockIdx.x * 256 + threadIdx.x;
  if (idx >= total) return;
  int c = idx % C;
  float v = (y[idx] - stats[c]) * stats[C + c] * gamma[c] + beta[c];
  v = v > 0.f ? v : (__expf(v) - 1.f);
  o[idx] = v;
}

extern "C" void kernel_launch(void* const* d_in, const int* in_sizes, int n_in,
                              void* d_out, int out_size, void* d_ws, size_t ws_size,
                              hipStream_t stream) {
  (void)in_sizes; (void)n_in; (void)out_size; (void)ws_size;
  const float* x   = (const float*)d_in[0];
  const int*   adj = (const int*)d_in[1];
  const float* W1  = (const float*)d_in[2];
  const float* a1s = (const float*)d_in[3];
  const float* a1d = (const float*)d_in[4];
  const float* lw1 = (const float*)d_in[5];
  const float* lb1 = (const float*)d_in[6];
  const float* g1  = (const float*)d_in[7];
  const float* be1 = (const float*)d_in[8];
  const float* W2  = (const float*)d_in[9];
  const float* a2s = (const float*)d_in[10];
  const float* a2d = (const float*)d_in[11];
  const float* lw2 = (const float*)d_in[12];
  const float* lb2 = (const float*)d_in[13];
  const float* g2  = (const float*)d_in[14];
  const float* be2 = (const float*)d_in[15];
  float* out = (float*)d_out;

  // ---- workspace (peak 18.6 MB, proven), liveness-checked overlays ----
  // timeline: mask | packA,packW -> mm1(h1) -> pack1/scores1 -> stats1 -> agg1(x1)
  //           -> gemm2(y1) -> bn(x2) -> gemm3(h2) -> pack2/scores2 -> stats2
  //           -> agg2(x3) -> gemm4(y2) -> bn(out)
  // NOTE: pkW must NOT overlap h1 (mm1 reads pkW while writing h1 — R7's NaN bug).
  char* w = (char*)d_ws;
  const size_t MB = 1u << 20;
  ull_t* mask = (ull_t*)(w + 0);            // [0,2) whole session
  float*    h1  = (float*)(w + 2 * MB);     // [2,10) f32; live mm1..scores1/pack1
  float*    y1  = (float*)(w + 2 * MB);     // [2,3)  overlay (gemm2 out; h1 dead)
  float*    x2  = (float*)(w + 3 * MB);     // [3,4)
  float*    h2  = (float*)(w + 4 * MB);     // [4,6)  dead after pack2/scores2
  ushort_t* pk2 = (ushort_t*)(w + 6 * MB);  // [6,7)  packed B tiles layer2 (1MB)
  ushort_t* pkW = (ushort_t*)(w + 7 * MB);  // [7,8)  W1 packed hi/lo; dead after mm1
  float*    x3  = (float*)(w + 7 * MB);     // [7,9)  overlay (agg2 out; pkW dead)
  float*    y2  = (float*)(w + 9 * MB);     // [9,9.25)
  ushort_t* pkA = (ushort_t*)(w + 10 * MB); // [10,18) x packed hi/lo; dead after mm1
  ushort_t* pk1 = (ushort_t*)(w + 10 * MB); // [10,14) overlay (pack1 out; pkA dead)
  bf16*     x1  = (bf16*)(w + 14 * MB);     // [14,18) overlay (agg1 out; pkA dead)
  float* es1 = (float*)(w + 18 * MB);       // aux
  float* ed1 = es1 + 16384;
  float* m1  = ed1 + 16384;
  float* li1 = m1 + 16384;
  float* es2 = li1 + 16384;
  float* ed2 = es2 + 16384;
  float* m2  = ed2 + 16384;
  float* li2 = m2 + 16384;
  float* st1 = li2 + 16384;
  float* st2 = st1 + 256;

  k_mask<<<NN, 256, 0, stream>>>(adj, mask);

  // ---- layer 1 GAT ----
  k_packA<<<1024, 256, 0, stream>>>(x, pkA);
  k_packW<<<128, 256, 0, stream>>>(W1, pkW);
  k_mm1<<<dim3(64, 4), 256, 0, stream>>>((const uint4*)pkA, (const uint4*)pkW, h1);
  k_pack<128, 256><<<dim3(NN / 32, H4), 256, 0, stream>>>(h1, pk1);
  k_scores<128><<<(NN * H4) / 256, 256, 0, stream>>>(h1, a1s, a1d, es1, ed1);
  k_stats<<<NN, 256, 0, stream>>>(es1, ed1, mask, m1, li1);
  k_agg_mfma<128, bf16><<<dim3(128, H4), 256, 0, stream>>>((const uint4*)pk1, es1, ed1, m1,
                                                           li1, mask, x1);

  // ---- linear + BN + ELU ----
  k_gemm<bf16><<<dim3(1, 64), 256, 0, stream>>>(x1, lw1, lb1, y1, NN, 512, 64);
  k_colstats<<<64, 256, 0, stream>>>(y1, st1, 64);
  k_bn_elu<<<(NN * 64) / 256, 256, 0, stream>>>(y1, st1, g1, be1, x2, 64, NN * 64);

  // ---- layer 2 GAT ----
  k_gemm<float><<<dim3(2, 64), 256, 0, stream>>>(x2, W2, nullptr, h2, NN, 64, 128);
  k_pack<32, 128><<<dim3(NN / 32, H4), 128, 0, stream>>>(h2, pk2);
  k_scores<32><<<(NN * H4) / 256, 256, 0, stream>>>(h2, a2s, a2d, es2, ed2);
  k_stats<<<NN, 256, 0, stream>>>(es2, ed2, mask, m2, li2);
  k_agg_mfma<32, float><<<dim3(128, H4), 256, 0, stream>>>((const uint4*)pk2, es2, ed2, m2,
                                                           li2, mask, x3);

  // ---- final linear + BN + ELU ----
  k_gemm<float><<<dim3(1, 64), 256, 0, stream>>>(x3, lw2, lb2, y2, NN, 128, 16);
  k_colstats<<<16, 256, 0, stream>>>(y2, st2, 16);
  k_bn_elu<<<(NN * 16) / 256, 256, 0, stream>>>(y2, st2, g2, be2, out, 16, NN * 16);
}

// Round 9
// 297.090 us; speedup vs baseline: 1.8997x; 1.4528x over previous
//
#include <hip/hip_runtime.h>
#include <hip/hip_bf16.h>
#include <stdint.h>

#define NN 4096
#define H4 4

typedef __hip_bfloat16 bf16;
typedef unsigned short ushort_t;
typedef unsigned long long ull_t;
typedef __attribute__((ext_vector_type(4))) float f32x4;
typedef __attribute__((ext_vector_type(8))) short s16x8;

__device__ __forceinline__ float cvt(float v) { return v; }
__device__ __forceinline__ float cvt(bf16 v) { return __bfloat162float(v); }
__device__ __forceinline__ ushort_t f2bf(float f) {
  unsigned u = __float_as_uint(f);
  return (ushort_t)((u + 0x7fff + ((u >> 16) & 1)) >> 16);
}
__device__ __forceinline__ float bf2f(ushort_t h) {
  return __uint_as_float((unsigned)h << 16);
}
__device__ __forceinline__ short2 pkbf(float a, float b) {
  union { __hip_bfloat162 h; short2 s; } u;
  u.h = __float22bfloat162_rn(make_float2(a, b));
  return u.s;
}
__device__ __forceinline__ s16x8 as_s16x8(uint4 v) {
  union { uint4 u; s16x8 s; } c; c.u = v; return c.s;
}

// ---------------- adj -> 64-bit row masks ----------------
__global__ __launch_bounds__(256) void k_mask(const int* __restrict__ adj,
                                              ull_t* __restrict__ mask) {
  int row = blockIdx.x, tid = threadIdx.x;
  int lane = tid & 63, wv = tid >> 6;
  const int* arow = adj + (size_t)row * NN;
  for (int c = 0; c < NN; c += 256) {
    int col = c + wv * 64 + lane;
    ull_t b = __ballot(arow[col] != 0);
    if (lane == 0) mask[row * 64 + (c >> 6) + wv] = b;
  }
}

// ---------------- tiled GEMM (fp32 VALU; only gemm3 uses it now) ----------------
__global__ __launch_bounds__(256) void k_gemm(const float* __restrict__ A,
                                              const float* __restrict__ B,
                                              const float* __restrict__ bias,
                                              float* __restrict__ C, int M, int K, int Nc) {
  __shared__ float As[16][68];
  __shared__ float Bs[16][68];
  int tid = threadIdx.x;
  int tx = tid & 15, ty = tid >> 4;
  int mBase = blockIdx.y * 64, nBase = blockIdx.x * 64;
  float acc[4][4] = {};
  for (int k0 = 0; k0 < K; k0 += 16) {
#pragma unroll
    for (int l = 0; l < 4; ++l) {
      int idx = l * 256 + tid;
      int m = idx >> 4, k = idx & 15;
      As[k][m] = A[(size_t)(mBase + m) * K + (k0 + k)];
    }
#pragma unroll
    for (int l = 0; l < 4; ++l) {
      int idx = l * 256 + tid;
      int k = idx >> 6, n = idx & 63;
      int gn = nBase + n;
      Bs[k][n] = (gn < Nc) ? B[(size_t)(k0 + k) * Nc + gn] : 0.f;
    }
    __syncthreads();
#pragma unroll
    for (int k = 0; k < 16; ++k) {
      float4 a = *(const float4*)&As[k][ty * 4];
      float4 b = *(const float4*)&Bs[k][tx * 4];
      float av[4] = {a.x, a.y, a.z, a.w};
      float bv[4] = {b.x, b.y, b.z, b.w};
#pragma unroll
      for (int r = 0; r < 4; ++r)
#pragma unroll
        for (int c = 0; c < 4; ++c) acc[r][c] += av[r] * bv[c];
    }
    __syncthreads();
  }
#pragma unroll
  for (int r = 0; r < 4; ++r) {
    int gm = mBase + ty * 4 + r;
#pragma unroll
    for (int c = 0; c < 4; ++c) {
      int gn = nBase + tx * 4 + c;
      if (gn < Nc) {
        float v = acc[r][c];
        if (bias) v += bias[gn];
        C[(size_t)gm * Nc + gn] = v;
      }
    }
  }
}

// ---------------- pack x[4096][512] into MFMA A-fragment tiles, bf16 hi/lo --------
#define APLANE (4096 * 512)
__global__ __launch_bounds__(256) void k_packA(const float* __restrict__ x,
                                               ushort_t* __restrict__ pkA) {
  int t = threadIdx.x;
  int w = t >> 6, lane = t & 63;
  int q = lane >> 4, nn = lane & 15;
  int tau = blockIdx.x * 4 + w;  // 4096 tiles: mt in [0,256), ks in [0,16)
  int mt = tau >> 4, ks = tau & 15;
  const float* src = &x[(size_t)(mt * 16 + nn) * 512 + ks * 32 + q * 8];
  float4 v0 = *(const float4*)src;
  float4 v1 = *(const float4*)(src + 4);
  float vv[8] = {v0.x, v0.y, v0.z, v0.w, v1.x, v1.y, v1.z, v1.w};
  ushort_t hi[8], lo[8];
#pragma unroll
  for (int u = 0; u < 8; ++u) {
    hi[u] = f2bf(vv[u]);
    lo[u] = f2bf(vv[u] - bf2f(hi[u]));
  }
  size_t idx = ((size_t)(mt * 16 + ks) * 64 + lane) * 8;
  *(uint4*)&pkA[idx] = *(uint4*)hi;
  *(uint4*)&pkA[APLANE + idx] = *(uint4*)lo;
}

// ---------------- pack W[KK][NC] into MFMA B-fragment tiles, bf16 hi/lo --------
// pk[((ct*(KK/32)+ks)*64+lane)*8+u] = bf16_part(W[ks*32+q*8+u][ct*16+nn]); T=(NC/16)*(KK/32) tiles
template <int KK, int NC>
__global__ __launch_bounds__(256) void k_packWg(const float* __restrict__ W,
                                                ushort_t* __restrict__ pk) {
  constexpr int KS = KK / 32;
  constexpr int T = (NC / 16) * KS;
  constexpr int PL = T * 512;
  int t = threadIdx.x;
  int w = t >> 6, lane = t & 63;
  int q = lane >> 4, nn = lane & 15;
  int tau = blockIdx.x * 4 + w;
  if (tau >= T) return;
  int ct = tau / KS, ks = tau % KS;
  ushort_t hi[8], lo[8];
#pragma unroll
  for (int u = 0; u < 8; ++u) {
    float v = W[(size_t)(ks * 32 + q * 8 + u) * NC + ct * 16 + nn];
    hi[u] = f2bf(v);
    lo[u] = f2bf(v - bf2f(hi[u]));
  }
  size_t idx = ((size_t)(ct * KS + ks) * 64 + lane) * 8;
  *(uint4*)&pk[idx] = *(uint4*)hi;
  *(uint4*)&pk[PL + idx] = *(uint4*)lo;
}

// ---------------- h1 = x @ W1 via split-bf16 MFMA (hi*hi + hi*lo + lo*hi) --------
__global__ __launch_bounds__(256, 1) void k_mm1(const uint4* __restrict__ pkA,
                                                const uint4* __restrict__ pkW,
                                                float* __restrict__ h1) {
  constexpr int APL4 = APLANE / 8;
  constexpr int WPL4 = (512 / 16) * (512 / 32) * 64;  // 32768 uint4
  int t = threadIdx.x;
  int w = t >> 6, lane = t & 63;
  int q = lane >> 4, nn = lane & 15;
  int mt0 = blockIdx.x * 4 + (w & 1) * 2;
  int ct0 = blockIdx.y * 8 + (w >> 1) * 4;
  f32x4 acc[2][4];
#pragma unroll
  for (int rt = 0; rt < 2; ++rt)
#pragma unroll
    for (int c = 0; c < 4; ++c)
#pragma unroll
      for (int k = 0; k < 4; ++k) acc[rt][c][k] = 0.f;
#pragma unroll
  for (int ks = 0; ks < 16; ++ks) {
    int ia0 = (mt0 * 16 + ks) * 64 + lane;
    int ia1 = ((mt0 + 1) * 16 + ks) * 64 + lane;
    uint4 ah0 = pkA[ia0], ah1 = pkA[ia1];
    uint4 al0 = pkA[APL4 + ia0], al1 = pkA[APL4 + ia1];
    uint4 bh[4], bl[4];
#pragma unroll
    for (int c = 0; c < 4; ++c) {
      int ib = ((ct0 + c) * 16 + ks) * 64 + lane;
      bh[c] = pkW[ib];
      bl[c] = pkW[WPL4 + ib];
    }
#pragma unroll
    for (int c = 0; c < 4; ++c) {
      acc[0][c] = __builtin_amdgcn_mfma_f32_16x16x32_bf16(as_s16x8(ah0), as_s16x8(bh[c]), acc[0][c], 0, 0, 0);
      acc[0][c] = __builtin_amdgcn_mfma_f32_16x16x32_bf16(as_s16x8(ah0), as_s16x8(bl[c]), acc[0][c], 0, 0, 0);
      acc[0][c] = __builtin_amdgcn_mfma_f32_16x16x32_bf16(as_s16x8(al0), as_s16x8(bh[c]), acc[0][c], 0, 0, 0);
      acc[1][c] = __builtin_amdgcn_mfma_f32_16x16x32_bf16(as_s16x8(ah1), as_s16x8(bh[c]), acc[1][c], 0, 0, 0);
      acc[1][c] = __builtin_amdgcn_mfma_f32_16x16x32_bf16(as_s16x8(ah1), as_s16x8(bl[c]), acc[1][c], 0, 0, 0);
      acc[1][c] = __builtin_amdgcn_mfma_f32_16x16x32_bf16(as_s16x8(al1), as_s16x8(bh[c]), acc[1][c], 0, 0, 0);
    }
  }
  int rowB = blockIdx.x * 64 + (w & 1) * 32;
#pragma unroll
  for (int rt = 0; rt < 2; ++rt)
#pragma unroll
    for (int c = 0; c < 4; ++c)
#pragma unroll
      for (int reg = 0; reg < 4; ++reg) {
        int gi = rowB + rt * 16 + q * 4 + reg;
        h1[(size_t)gi * 512 + (ct0 + c) * 16 + nn] = acc[rt][c][reg];
      }
}

// ---------------- pack h[N][H4*F] f32 into MFMA B-fragment tiles (bf16) --------
template <int F, int TB>
__global__ __launch_bounds__(TB) void k_pack(const float* __restrict__ h,
                                             ushort_t* __restrict__ pk) {
  constexpr int CTW = TB / 64;
  int t = threadIdx.x;
  int lane = t & 63, ctw = t >> 6;
  int q = lane >> 4, nn = lane & 15;
  int ks = blockIdx.x, hd = blockIdx.y;
#pragma unroll
  for (int ct = ctw; ct < F / 16; ct += CTW) {
    ushort_t v[8];
#pragma unroll
    for (int u = 0; u < 8; ++u)
      v[u] = f2bf(h[(size_t)(ks * 32 + q * 8 + u) * (H4 * F) + hd * F + ct * 16 + nn]);
    *(uint4*)&pk[((((size_t)hd * (F / 16) + ct) * (NN / 32) + ks) * 64 + lane) * 8] =
        *(uint4*)v;
  }
}

// ---------------- attention scores ----------------
template <int F>
__global__ __launch_bounds__(256) void k_scores(const float* __restrict__ h,
                                                const float* __restrict__ a_s,
                                                const float* __restrict__ a_d,
                                                float* __restrict__ es, float* __restrict__ ed) {
  int idx = blockIdx.x * 256 + threadIdx.x;
  if (idx >= NN * H4) return;
  int n = idx >> 2, hd = idx & 3;
  const float* hp = h + (size_t)n * (H4 * F) + hd * F;
  const float* sp = a_s + hd * F;
  const float* dp = a_d + hd * F;
  float ss = 0.f, sd = 0.f;
#pragma unroll 4
  for (int f = 0; f < F; ++f) {
    float v = hp[f];
    ss += v * sp[f];
    sd += v * dp[f];
  }
  es[hd * NN + n] = ss;
  ed[hd * NN + n] = sd;
}

// ---------------- MFMA aggregation with fused softmax normalization ----------------
// u_ij = maskbit ? exp(min(lrelu(es_i+ed_j), 80)) : 0   (no max-sub: z in [-2,~9] by
// construction — weights ~N(0,1) scaling; clamp is inert insurance). Row-sum rs
// accumulated in-lane during A-build, reduced over q-quads (2 shuffles) + 4 j-split
// waves (LDS), epilogue divides. Output written directly in packed MFMA-A layout
// for the following linear layer (OUTM=0: single bf16 plane; OUTM=1: hi/lo planes).
__device__ __forceinline__ s16x8 build_a(float esi, unsigned byt, float4 ea, float4 eb,
                                         float& rs) {
  float ev[8] = {ea.x, ea.y, ea.z, ea.w, eb.x, eb.y, eb.z, eb.w};
  union { s16x8 v; short2 p[4]; } A;
#pragma unroll
  for (int tp = 0; tp < 4; ++tp) {
    float z0 = esi + ev[2 * tp];
    z0 = fmaxf(z0, 0.2f * z0);
    float w0 = (byt & (1u << (2 * tp))) ? __expf(fminf(z0, 80.f)) : 0.f;
    float z1 = esi + ev[2 * tp + 1];
    z1 = fmaxf(z1, 0.2f * z1);
    float w1 = (byt & (1u << (2 * tp + 1))) ? __expf(fminf(z1, 80.f)) : 0.f;
    rs += w0 + w1;
    A.p[tp] = pkbf(w0, w1);
  }
  return A.v;
}

template <int F, int OUTM>
__global__ __launch_bounds__(256, 2) void k_agg_mfma(
    const uint4* __restrict__ pk, const float* __restrict__ es,
    const float* __restrict__ ed, const ull_t* __restrict__ mask,
    ushort_t* __restrict__ pkOut) {
  constexpr int CT = F / 16;
  constexpr int KSO = (H4 * F) / 32;            // out-tile k-slices per row-tile
  constexpr int OPL = NN * H4 * F;              // out plane stride (elements)
  __shared__ float red[2 * 32 * F];
  __shared__ float rsred[32 * 4];
  int t = threadIdx.x;
  int w = t >> 6, lane = t & 63;
  int q = lane >> 4, nn = lane & 15;
  int hd = blockIdx.y;
  int rowBase = blockIdx.x * 32;
  int jBase = w * (NN / 4);
  int ia0 = rowBase + nn, ia1 = rowBase + 16 + nn;
  float es0 = es[hd * NN + ia0];
  float es1 = es[hd * NN + ia1];
  const ull_t* mk0p = mask + (size_t)ia0 * 64;
  const ull_t* mk1p = mask + (size_t)ia1 * 64;
  const float* edh = ed + hd * NN;

  f32x4 acc[2][CT];
#pragma unroll
  for (int rt = 0; rt < 2; ++rt)
#pragma unroll
    for (int cc = 0; cc < CT; ++cc)
#pragma unroll
      for (int k = 0; k < 4; ++k) acc[rt][cc][k] = 0.f;
  float rs0 = 0.f, rs1 = 0.f;

  for (int jc = 0; jc < NN / 4 / 64; ++jc) {
    int j0 = jBase + jc * 64;
    int ks0 = j0 >> 5;
    uint4 bv[2][CT];
#pragma unroll
    for (int s = 0; s < 2; ++s)
#pragma unroll
      for (int cc = 0; cc < CT; ++cc)
        bv[s][cc] = pk[(size_t)((hd * CT + cc) * (NN / 32) + ks0 + s) * 64 + lane];
    ull_t mk0 = mk0p[j0 >> 6], mk1 = mk1p[j0 >> 6];
    float4 e0 = *(const float4*)&edh[j0 + q * 8];
    float4 e1 = *(const float4*)&edh[j0 + q * 8 + 4];
    float4 e2 = *(const float4*)&edh[j0 + 32 + q * 8];
    float4 e3 = *(const float4*)&edh[j0 + 32 + q * 8 + 4];
    s16x8 a00 = build_a(es0, (unsigned)(mk0 >> (q * 8)) & 0xffu, e0, e1, rs0);
    s16x8 a01 = build_a(es0, (unsigned)(mk0 >> (32 + q * 8)) & 0xffu, e2, e3, rs0);
    s16x8 a10 = build_a(es1, (unsigned)(mk1 >> (q * 8)) & 0xffu, e0, e1, rs1);
    s16x8 a11 = build_a(es1, (unsigned)(mk1 >> (32 + q * 8)) & 0xffu, e2, e3, rs1);
#pragma unroll
    for (int cc = 0; cc < CT; ++cc)
      acc[0][cc] = __builtin_amdgcn_mfma_f32_16x16x32_bf16(a00, as_s16x8(bv[0][cc]), acc[0][cc], 0, 0, 0);
#pragma unroll
    for (int cc = 0; cc < CT; ++cc)
      acc[0][cc] = __builtin_amdgcn_mfma_f32_16x16x32_bf16(a01, as_s16x8(bv[1][cc]), acc[0][cc], 0, 0, 0);
#pragma unroll
    for (int cc = 0; cc < CT; ++cc)
      acc[1][cc] = __builtin_amdgcn_mfma_f32_16x16x32_bf16(a10, as_s16x8(bv[0][cc]), acc[1][cc], 0, 0, 0);
#pragma unroll
    for (int cc = 0; cc < CT; ++cc)
      acc[1][cc] = __builtin_amdgcn_mfma_f32_16x16x32_bf16(a11, as_s16x8(bv[1][cc]), acc[1][cc], 0, 0, 0);
  }

  // ---- row-sum reduce over q-quads, stash per-wave into LDS ----
  rs0 += __shfl_xor(rs0, 16, 64); rs0 += __shfl_xor(rs0, 32, 64);
  rs1 += __shfl_xor(rs1, 16, 64); rs1 += __shfl_xor(rs1, 32, 64);
  if (q == 0) {
    rsred[nn * 4 + w] = rs0;
    rsred[(16 + nn) * 4 + w] = rs1;
  }

  // ---- cross-wave acc reduce: (0,1)->region0, (2,3)->region1, then 0+=2 ----
#define IDX(rt, cc, reg) ((rt * 16 + q * 4 + reg) * F + cc * 16 + nn)
  if (w == 1 || w == 3) {
    int base = (w >> 1) * 32 * F;
#pragma unroll
    for (int rt = 0; rt < 2; ++rt)
#pragma unroll
      for (int cc = 0; cc < CT; ++cc)
#pragma unroll
        for (int reg = 0; reg < 4; ++reg) red[base + IDX(rt, cc, reg)] = acc[rt][cc][reg];
  }
  __syncthreads();
  if (w == 0 || w == 2) {
    int base = (w >> 1) * 32 * F;
#pragma unroll
    for (int rt = 0; rt < 2; ++rt)
#pragma unroll
      for (int cc = 0; cc < CT; ++cc)
#pragma unroll
        for (int reg = 0; reg < 4; ++reg) acc[rt][cc][reg] += red[base + IDX(rt, cc, reg)];
  }
  if (w == 2) {
#pragma unroll
    for (int rt = 0; rt < 2; ++rt)
#pragma unroll
      for (int cc = 0; cc < CT; ++cc)
#pragma unroll
        for (int reg = 0; reg < 4; ++reg) red[32 * F + IDX(rt, cc, reg)] = acc[rt][cc][reg];
  }
  __syncthreads();
  if (w == 0) {
    float rinv[2][4];
#pragma unroll
    for (int rt = 0; rt < 2; ++rt)
#pragma unroll
      for (int reg = 0; reg < 4; ++reg) {
        int row = rt * 16 + q * 4 + reg;
        float4 rv = *(float4*)&rsred[row * 4];
        float s = (rv.x + rv.y) + (rv.z + rv.w);
        rinv[rt][reg] = (s > 0.f) ? 1.f / s : 0.f;
      }
#pragma unroll
    for (int rt = 0; rt < 2; ++rt)
#pragma unroll
      for (int cc = 0; cc < CT; ++cc)
#pragma unroll
        for (int reg = 0; reg < 4; ++reg) {
          float v = (acc[rt][cc][reg] + red[32 * F + IDX(rt, cc, reg)]) * rinv[rt][reg];
          int gi = rowBase + rt * 16 + q * 4 + reg;
          int c = hd * F + cc * 16 + nn;
          int mt = gi >> 4, rowin = gi & 15;
          int ks = c >> 5, qp = (c >> 3) & 3, u = c & 7;
          size_t idx = (((size_t)mt * KSO + ks) * 64 + qp * 16 + rowin) * 8 + u;
          ushort_t hi = f2bf(v);
          pkOut[idx] = hi;
          if (OUTM == 1) pkOut[OPL + idx] = f2bf(v - bf2f(hi));
        }
  }
#undef IDX
}

// ---------------- y1 = pkX1(bf16) @ lw1(hi/lo) + lb1, MFMA, K-split x2 ----------------
__global__ __launch_bounds__(256) void k_mm2(const uint4* __restrict__ pkX,
                                             const uint4* __restrict__ pkW,
                                             const float* __restrict__ bias,
                                             float* __restrict__ y) {
  constexpr int WPL4 = 4 * 16 * 64;  // lw1: 4 ct x 16 ks tiles
  __shared__ float red[2 * 16 * 64];
  int t = threadIdx.x;
  int w = t >> 6, lane = t & 63;
  int q = lane >> 4, nn = lane & 15;
  int mt = blockIdx.x * 2 + (w & 1);
  int kh = w >> 1;
  f32x4 acc[4];
#pragma unroll
  for (int c = 0; c < 4; ++c)
#pragma unroll
    for (int k = 0; k < 4; ++k) acc[c][k] = 0.f;
#pragma unroll
  for (int k8 = 0; k8 < 8; ++k8) {
    int ks = kh * 8 + k8;
    uint4 a = pkX[(mt * 16 + ks) * 64 + lane];
#pragma unroll
    for (int c = 0; c < 4; ++c) {
      uint4 bh = pkW[(c * 16 + ks) * 64 + lane];
      uint4 bl = pkW[WPL4 + (c * 16 + ks) * 64 + lane];
      acc[c] = __builtin_amdgcn_mfma_f32_16x16x32_bf16(as_s16x8(a), as_s16x8(bh), acc[c], 0, 0, 0);
      acc[c] = __builtin_amdgcn_mfma_f32_16x16x32_bf16(as_s16x8(a), as_s16x8(bl), acc[c], 0, 0, 0);
    }
  }
  int base = (w & 1) * 1024;
  if (kh == 1) {
#pragma unroll
    for (int c = 0; c < 4; ++c)
#pragma unroll
      for (int reg = 0; reg < 4; ++reg)
        red[base + (q * 4 + reg) * 64 + c * 16 + nn] = acc[c][reg];
  }
  __syncthreads();
  if (kh == 0) {
#pragma unroll
    for (int c = 0; c < 4; ++c)
#pragma unroll
      for (int reg = 0; reg < 4; ++reg) {
        float v = acc[c][reg] + red[base + (q * 4 + reg) * 64 + c * 16 + nn] + bias[c * 16 + nn];
        y[(size_t)(mt * 16 + q * 4 + reg) * 64 + c * 16 + nn] = v;
      }
  }
}

// ---------------- y2 = pkX3(hi/lo) @ lw2(hi/lo) + lb2, MFMA ----------------
__global__ __launch_bounds__(256) void k_mm4(const uint4* __restrict__ pkX,
                                             const uint4* __restrict__ pkW,
                                             const float* __restrict__ bias,
                                             float* __restrict__ y) {
  constexpr int XPL4 = 256 * 4 * 64;  // x3: 256 mt x 4 ks tiles
  constexpr int WPL4 = 1 * 4 * 64;    // lw2: 1 ct x 4 ks tiles
  int t = threadIdx.x;
  int w = t >> 6, lane = t & 63;
  int q = lane >> 4, nn = lane & 15;
  int mt = blockIdx.x * 4 + w;
  f32x4 acc;
#pragma unroll
  for (int k = 0; k < 4; ++k) acc[k] = 0.f;
#pragma unroll
  for (int ks = 0; ks < 4; ++ks) {
    uint4 ah = pkX[(mt * 4 + ks) * 64 + lane];
    uint4 al = pkX[XPL4 + (mt * 4 + ks) * 64 + lane];
    uint4 bh = pkW[ks * 64 + lane];
    uint4 bl = pkW[WPL4 + ks * 64 + lane];
    acc = __builtin_amdgcn_mfma_f32_16x16x32_bf16(as_s16x8(ah), as_s16x8(bh), acc, 0, 0, 0);
    acc = __builtin_amdgcn_mfma_f32_16x16x32_bf16(as_s16x8(ah), as_s16x8(bl), acc, 0, 0, 0);
    acc = __builtin_amdgcn_mfma_f32_16x16x32_bf16(as_s16x8(al), as_s16x8(bh), acc, 0, 0, 0);
  }
  float b = bias[nn];
#pragma unroll
  for (int reg = 0; reg < 4; ++reg)
    y[(size_t)(mt * 16 + q * 4 + reg) * 16 + nn] = acc[reg] + b;
}

// ---------------- per-column mean / inv-std ----------------
__global__ __launch_bounds__(256) void k_colstats(const float* __restrict__ y,
                                                  float* __restrict__ stats, int C) {
  int c = blockIdx.x, tid = threadIdx.x;
  float s = 0.f, s2 = 0.f;
  for (int r = tid; r < NN; r += 256) {
    float v = y[(size_t)r * C + c];
    s += v;
    s2 += v * v;
  }
  __shared__ float sh[256], sh2[256];
  sh[tid] = s; sh2[tid] = s2;
  __syncthreads();
  for (int off = 128; off; off >>= 1) {
    if (tid < off) { sh[tid] += sh[tid + off]; sh2[tid] += sh2[tid + off]; }
    __syncthreads();
  }
  if (tid == 0) {
    float mean = sh[0] * (1.f / NN);
    float var = sh2[0] * (1.f / NN) - mean * mean;
    stats[c] = mean;
    stats[C + c] = rsqrtf(fmaxf(var, 0.f) + 1e-5f);
  }
}

// ---------------- BN + ELU ----------------
__global__ __launch_bounds__(256) void k_bn_elu(const float* __restrict__ y,
                                                const float* __restrict__ stats,
                                                const float* __restrict__ gamma,
                                                const float* __restrict__ beta,
                                                float* __restrict__ o, int C, int total) {
  int idx = blockIdx.x * 256 + threadIdx.x;
  if (idx >= total) return;
  int c = idx % C;
  float v = (y[idx] - stats[c]) * stats[C + c] * gamma[c] + beta[c];
  v = v > 0.f ? v : (__expf(v) - 1.f);
  o[idx] = v;
}

extern "C" void kernel_launch(void* const* d_in, const int* in_sizes, int n_in,
                              void* d_out, int out_size, void* d_ws, size_t ws_size,
                              hipStream_t stream) {
  (void)in_sizes; (void)n_in; (void)out_size; (void)ws_size;
  const float* x   = (const float*)d_in[0];
  const int*   adj = (const int*)d_in[1];
  const float* W1  = (const float*)d_in[2];
  const float* a1s = (const float*)d_in[3];
  const float* a1d = (const float*)d_in[4];
  const float* lw1 = (const float*)d_in[5];
  const float* lb1 = (const float*)d_in[6];
  const float* g1  = (const float*)d_in[7];
  const float* be1 = (const float*)d_in[8];
  const float* W2  = (const float*)d_in[9];
  const float* a2s = (const float*)d_in[10];
  const float* a2d = (const float*)d_in[11];
  const float* lw2 = (const float*)d_in[12];
  const float* lb2 = (const float*)d_in[13];
  const float* g2  = (const float*)d_in[14];
  const float* be2 = (const float*)d_in[15];
  float* out = (float*)d_out;

  // ---- workspace: LINEAR layout, no overlays (ws >= 268 MB; ~36 MB used) ----
  char* w = (char*)d_ws;
  const size_t MB = 1u << 20;
  ull_t*    mask  = (ull_t*)(w + 0);              // 2 MB
  ushort_t* pkA   = (ushort_t*)(w + 2 * MB);      // 8 MB (x packed hi/lo)
  ushort_t* pkW1  = (ushort_t*)(w + 10 * MB);     // 1 MB
  float*    h1    = (float*)(w + 11 * MB);        // 8 MB
  ushort_t* pk1   = (ushort_t*)(w + 19 * MB);     // 4 MB (h1 B-tiles)
  float*    es1   = (float*)(w + 23 * MB);        // 64 KB
  float*    ed1   = (float*)(w + 23 * MB + 65536);
  ushort_t* pkX1  = (ushort_t*)(w + 24 * MB);     // 4 MB (x1 A-tiles, single plane)
  ushort_t* pkLW1 = (ushort_t*)(w + 28 * MB);     // 128 KB (hi/lo)
  float*    y1    = (float*)(w + 29 * MB);        // 1 MB
  float*    x2    = (float*)(w + 30 * MB);        // 1 MB
  float*    h2    = (float*)(w + 31 * MB);        // 2 MB
  ushort_t* pk2   = (ushort_t*)(w + 33 * MB);     // 1 MB (h2 B-tiles)
  float*    es2   = (float*)(w + 34 * MB);        // 64 KB
  float*    ed2   = (float*)(w + 34 * MB + 65536);
  ushort_t* pkX3  = (ushort_t*)(w + 35 * MB);     // 2 MB (x3 A-tiles hi/lo)
  ushort_t* pkLW2 = (ushort_t*)(w + 37 * MB);     // 8 KB (hi/lo)
  float*    y2    = (float*)(w + 37 * MB + 131072);  // 256 KB
  float*    st1   = (float*)(w + 38 * MB);        // 512 B
  float*    st2   = (float*)(w + 38 * MB + 4096);

  k_mask<<<NN, 256, 0, stream>>>(adj, mask);

  // ---- layer 1 GAT ----
  k_packA<<<1024, 256, 0, stream>>>(x, pkA);
  k_packWg<512, 512><<<128, 256, 0, stream>>>(W1, pkW1);
  k_packWg<512, 64><<<16, 256, 0, stream>>>(lw1, pkLW1);
  k_packWg<128, 16><<<1, 256, 0, stream>>>(lw2, pkLW2);
  k_mm1<<<dim3(64, 4), 256, 0, stream>>>((const uint4*)pkA, (const uint4*)pkW1, h1);
  k_pack<128, 256><<<dim3(NN / 32, H4), 256, 0, stream>>>(h1, pk1);
  k_scores<128><<<(NN * H4) / 256, 256, 0, stream>>>(h1, a1s, a1d, es1, ed1);
  k_agg_mfma<128, 0><<<dim3(128, H4), 256, 0, stream>>>((const uint4*)pk1, es1, ed1, mask,
                                                        pkX1);

  // ---- linear + BN + ELU ----
  k_mm2<<<128, 256, 0, stream>>>((const uint4*)pkX1, (const uint4*)pkLW1, lb1, y1);
  k_colstats<<<64, 256, 0, stream>>>(y1, st1, 64);
  k_bn_elu<<<(NN * 64) / 256, 256, 0, stream>>>(y1, st1, g1, be1, x2, 64, NN * 64);

  // ---- layer 2 GAT ----
  k_gemm<<<dim3(2, 64), 256, 0, stream>>>(x2, W2, nullptr, h2, NN, 64, 128);
  k_pack<32, 128><<<dim3(NN / 32, H4), 128, 0, stream>>>(h2, pk2);
  k_scores<32><<<(NN * H4) / 256, 256, 0, stream>>>(h2, a2s, a2d, es2, ed2);
  k_agg_mfma<32, 1><<<dim3(128, H4), 256, 0, stream>>>((const uint4*)pk2, es2, ed2, mask,
                                                       pkX3);

  // ---- final linear + BN + ELU ----
  k_mm4<<<64, 256, 0, stream>>>((const uint4*)pkX3, (const uint4*)pkLW2, lb2, y2);
  k_colstats<<<16, 256, 0, stream>>>(y2, st2, 16);
  k_bn_elu<<<(NN * 16) / 256, 256, 0, stream>>>(y2, st2, g2, be2, out, 16, NN * 16);
}